// Round 12
// baseline (193.113 us; speedup 1.0000x reference)
//
#include <hip/hip_runtime.h>
#include <hip/hip_bf16.h>

// Problem constants
#define NB    2048   // batch
#define SS    200    // seq len
#define NTIL  13     // s-tiles of 16 (208 padded)
#define DSEQ  256
#define DITEM 64
#define AA    128    // attn dim (H=1, HD=128)

typedef __bf16 bf16x8 __attribute__((ext_vector_type(8)));
typedef float  f32x4  __attribute__((ext_vector_type(4)));

__device__ __forceinline__ float prelu_f(float x, float a) { return x >= 0.f ? x : a * x; }

// 16-lane reduce via DPP row_ror — VALU pipe only; result valid in all 16 lanes.
#define ROR_F(x, n) __int_as_float(__builtin_amdgcn_update_dpp(0, __float_as_int(x), 0x120 + (n), 0xf, 0xf, true))
__device__ __forceinline__ float row_sum16(float x) {
    x += ROR_F(x, 1); x += ROR_F(x, 2); x += ROR_F(x, 4); x += ROR_F(x, 8);
    return x;
}
__device__ __forceinline__ float row_max16(float x) {
    x = fmaxf(x, ROR_F(x, 1)); x = fmaxf(x, ROR_F(x, 2));
    x = fmaxf(x, ROR_F(x, 4)); x = fmaxf(x, ROR_F(x, 8));
    return x;
}

// ---------------- prep: W_k|W_v -> bf16 [256 rows][512B], XOR-swizzled within rows
// element (a,d) stored at byte (d*2) ^ ((a&7)<<4) of row a
__global__ void prep_kernel(const float* __restrict__ Wk, const float* __restrict__ Wv,
                            __hip_bfloat16* __restrict__ Wb) {
    int idx = blockIdx.x * 256 + threadIdx.x;   // 256 blocks -> 65536
    int a = idx >> 8, d = idx & 255;
    float v = (a < 128) ? Wk[a * 256 + d] : Wv[(a - 128) * 256 + d];
    int boff = (d * 2) ^ ((a & 7) << 4);
    Wb[a * 256 + (boff >> 1)] = __float2bfloat16(v);
}

// per-thread staging: thread handles row srow, 32B chunk `chunk` of the 16x256 f32 tile
#define ISSUE(tt)                                                               \
    {                                                                           \
        int r_ = (tt) * 16 + srow; r_ = r_ < SS ? r_ : SS - 1;                  \
        const float* xp_ = X + ((size_t)b * SS + r_) * DSEQ + chunk * 8;        \
        stlo = *reinterpret_cast<const f32x4*>(xp_);                            \
        sthi = *reinterpret_cast<const f32x4*>(xp_ + 4);                        \
    }

#define STAGE(buf)                                                              \
    {                                                                           \
        bf16x8 v_;                                                              \
        v_[0] = (__bf16)stlo[0]; v_[1] = (__bf16)stlo[1];                       \
        v_[2] = (__bf16)stlo[2]; v_[3] = (__bf16)stlo[3];                       \
        v_[4] = (__bf16)sthi[0]; v_[5] = (__bf16)sthi[1];                       \
        v_[6] = (__bf16)sthi[2]; v_[7] = (__bf16)sthi[3];                       \
        *reinterpret_cast<bf16x8*>(xbase + (buf) * 8192 + wr_off) = v_;         \
    }

// deferred online-softmax + V-fold of tile `tp` (scores of tp are in sp[tp&1])
#define SMFOLD(tp)                                                              \
    {                                                                           \
        const int q_ = (tp) & 1;                                                \
        const int s0_ = (tp) * 16;                                              \
        f32x4 r0_ = *reinterpret_cast<const f32x4*>(&sp[q_][c][0]);             \
        f32x4 r1_ = *reinterpret_cast<const f32x4*>(&sp[q_][c][4]);             \
        float sc_ = (r0_[0]+r0_[1]+r0_[2]+r0_[3]+r1_[0]+r1_[1]+r1_[2]+r1_[3]) * inv_scale; \
        sc_ = mask_lds[s0_ + c] ? -1e9f : sc_;                                  \
        if (tid < 16) score_buf[s0_ + tid] = sc_;                               \
        float tmax_ = row_max16(sc_);                                           \
        float nm_ = fmaxf(m, tmax_);                                            \
        float fs_ = __expf(m - nm_);                                            \
        float e_  = __expf(sc_ - nm_);                                          \
        float ls_ = row_sum16(e_);                                              \
        l = l * fs_ + ls_; m = nm_;                                             \
        oacc *= fs_;                                                            \
        _Pragma("unroll")                                                       \
        for (int i_ = 0; i_ < 4; i_++) {                                        \
            float ew_ = __shfl(e_, (lane & 48) | (rg * 4 + i_), 64);            \
            oacc += ew_ * prelu_f(aVp[i_], pa);                                 \
        }                                                                       \
    }

// ---------------- main: one BLOCK (8 waves) per batch row; cooperative LDS staging
// K weight frags in VGPRs; V weight frags streamed from L2 (Wb is 128 KB,
// L2-resident, shared by all blocks) -> ~90-reg live set -> 2 blocks/CU.
__global__ __launch_bounds__(512)
void pool_main(
    const float* __restrict__ X,      // [2048,200,256]
    const int*   __restrict__ maskp,  // [2048,200] 1 = pad
    const float* __restrict__ temb,   // [2048,64]
    const float* __restrict__ Wq,     // [128,64]
    const float* __restrict__ Wker,   // [128,128]
    const float* __restrict__ ffnW,   // [256,128]
    const float* __restrict__ ffnb,   // [256]
    const float* __restrict__ prelu_a,
    const __hip_bfloat16* __restrict__ Wb,  // ws: swizzled bf16 weights [256][256]
    float* __restrict__ out)          // [2048*256] ffn, then [2048*200] attn
{
    __shared__ __hip_bfloat16 Xt[2][16][256];    // 16 KB, dbuf bf16 X tile (swizzled)
    __shared__ float sp[2][16][8];               // [par][s][wave] score partials
    __shared__ float score_buf[208];
    __shared__ float out_vec[AA];
    __shared__ float tq[DITEM];
    __shared__ float Qv[AA];
    __shared__ float uv[AA];
    __shared__ int   mask_lds[208];

    const int tid  = threadIdx.x;
    const int w    = tid >> 6;        // wave 0..7
    const int lane = tid & 63;
    const int c    = lane & 15;       // A-row (s in tile) == D-col (col within wave's 16)
    const int rg   = lane >> 4;       // k-group / D-row-group
    const int b    = blockIdx.x;
    const float pa = *prelu_a;
    const float inv_scale = 0.08838834764831845f;  // 1/sqrt(128)

    const int srow  = tid >> 5;       // staging row 0..15
    const int chunk = tid & 31;       // 32B chunk in row
    const int wr_off = srow * 512 + ((chunk * 16) ^ ((srow & 7) << 4));
    char* xbase = (char*)&Xt[0][0][0];
    const int rswz = (c & 7) << 4;

    // ---- K weight fragments -> VGPRs; V stays in L2, streamed per tile
    bf16x8 wk[8];
    const char* kb = (const char*)Wb + (size_t)(16 * w + c) * 512;
    const char* vb = kb + 65536;
    #pragma unroll
    for (int k = 0; k < 8; k++)
        wk[k] = *reinterpret_cast<const bf16x8*>(kb + ((k * 64 + rg * 16) ^ rswz));

    // ---- small staging + X tile-0 issue
    if (tid < DITEM) tq[tid] = temb[(size_t)b * DITEM + tid];
    if (tid < 208)   mask_lds[tid] = (tid < SS) ? maskp[(size_t)b * SS + tid] : 1;
    f32x4 stlo, sthi;
    ISSUE(0);
    __syncthreads();

    // ---- Q = prelu(W_q @ t)
    if (tid < AA) {
        float acc = 0.f;
        #pragma unroll
        for (int d4 = 0; d4 < 16; d4++) {
            f32x4 tv = *reinterpret_cast<const f32x4*>(&tq[d4 * 4]);
            f32x4 wq4 = *reinterpret_cast<const f32x4*>(Wq + (size_t)tid * DITEM + d4 * 4);
            acc += wq4[0]*tv[0] + wq4[1]*tv[1] + wq4[2]*tv[2] + wq4[3]*tv[3];
        }
        Qv[tid] = prelu_f(acc, pa);
    }
    __syncthreads();

    // ---- u = W_kernel @ Q
    if (tid < AA) {
        float acc = 0.f;
        #pragma unroll
        for (int d4 = 0; d4 < 32; d4++) {
            f32x4 qv = *reinterpret_cast<const f32x4*>(&Qv[d4 * 4]);
            f32x4 wv4 = *reinterpret_cast<const f32x4*>(Wker + (size_t)tid * AA + d4 * 4);
            acc += wv4[0]*qv[0] + wv4[1]*qv[1] + wv4[2]*qv[2] + wv4[3]*qv[3];
        }
        uv[tid] = acc;
    }
    __syncthreads();
    const float uwK = uv[16 * w + c];

    // tile 0 -> LDS
    STAGE(0);
    __syncthreads();

    // ---- main loop: 1 barrier per tile, deferred softmax
    float m = -INFINITY, l = 0.f, oacc = 0.f;
    f32x4 aVp = {0.f, 0.f, 0.f, 0.f};

    for (int t = 0; t < NTIL; t++) {
        if (t + 1 < NTIL) ISSUE(t + 1);

        const char* rb = xbase + (t & 1) * 8192 + c * 512;

        // deferred softmax + V-fold of tile t-1
        if (t > 0) SMFOLD(t - 1);

        // K/V MFMA: af read from LDS, V-frag from L2, both consumed immediately
        f32x4 aK = {0.f, 0.f, 0.f, 0.f};
        f32x4 aV = {0.f, 0.f, 0.f, 0.f};
        #pragma unroll
        for (int k = 0; k < 8; k++) {
            const int o = (k * 64 + rg * 16) ^ rswz;
            bf16x8 af = *reinterpret_cast<const bf16x8*>(rb + o);
            bf16x8 bv = *reinterpret_cast<const bf16x8*>(vb + o);   // L2 hit
            aK = __builtin_amdgcn_mfma_f32_16x16x32_bf16(af, wk[k], aK, 0, 0, 0);
            aV = __builtin_amdgcn_mfma_f32_16x16x32_bf16(af, bv,    aV, 0, 0, 0);
        }
        float pr[4];
        #pragma unroll
        for (int i = 0; i < 4; i++) pr[i] = row_sum16(prelu_f(aK[i], pa) * uwK);
        if (c == 0) {
            #pragma unroll
            for (int i = 0; i < 4; i++) sp[t & 1][rg * 4 + i][w] = pr[i];
        }
        aVp = aV;

        // stage tile t+1 into the other buffer (its last readers finished at t-1)
        if (t + 1 < NTIL) STAGE((t + 1) & 1);
        __syncthreads();
    }

    // ---- epilogue: fold last tile, reduce, outputs
    SMFOLD(NTIL - 1);
    oacc += __shfl_xor(oacc, 16, 64);
    oacc += __shfl_xor(oacc, 32, 64);
    const float invl = 1.0f / l;
    if (lane < 16) out_vec[16 * w + lane] = oacc * invl;
    __syncthreads();

    // attn output [b][200]
    if (tid < SS)
        out[(size_t)NB * DSEQ + (size_t)b * SS + tid] = __expf(score_buf[tid] - m) * invl;

    // FFN: out[o] = prelu(b[o] + sum_a ov[a]*ffnW[o][a])
    if (tid < DSEQ) {
        float acc = ffnb[tid];
        #pragma unroll 8
        for (int a4 = 0; a4 < 32; a4++) {
            f32x4 ov = *reinterpret_cast<const f32x4*>(&out_vec[a4 * 4]);
            f32x4 wv4 = *reinterpret_cast<const f32x4*>(ffnW + (size_t)tid * AA + a4 * 4);
            acc += wv4[0]*ov[0] + wv4[1]*ov[1] + wv4[2]*ov[2] + wv4[3]*ov[3];
        }
        out[(size_t)b * DSEQ + tid] = prelu_f(acc, pa);
    }
}

extern "C" void kernel_launch(void* const* d_in, const int* in_sizes, int n_in,
                              void* d_out, int out_size, void* d_ws, size_t ws_size,
                              hipStream_t stream) {
    const float* X    = (const float*)d_in[0];
    const int*   mask = (const int*)  d_in[1];
    const float* temb = (const float*)d_in[2];
    const float* Wq   = (const float*)d_in[3];
    const float* Wk   = (const float*)d_in[4];
    const float* Wv   = (const float*)d_in[5];
    const float* Wker = (const float*)d_in[6];
    const float* ffnW = (const float*)d_in[7];
    const float* ffnb = (const float*)d_in[8];
    const float* pa   = (const float*)d_in[9];
    float* out = (float*)d_out;

    __hip_bfloat16* Wb = (__hip_bfloat16*)d_ws;

    prep_kernel<<<256, 256, 0, stream>>>(Wk, Wv, Wb);
    pool_main<<<NB, 512, 0, stream>>>(X, mask, temb, Wq, Wker, ffnW, ffnb, pa, Wb, out);
}

// Round 13
// 167.896 us; speedup vs baseline: 1.1502x; 1.1502x over previous
//
#include <hip/hip_runtime.h>
#include <hip/hip_bf16.h>

// Problem constants
#define NB    2048   // batch
#define SS    200    // seq len
#define NTIL  13     // s-tiles of 16 (208 padded)
#define DSEQ  256
#define DITEM 64
#define AA    128    // attn dim (H=1, HD=128)

typedef __bf16 bf16x8 __attribute__((ext_vector_type(8)));
typedef float  f32x4  __attribute__((ext_vector_type(4)));

__device__ __forceinline__ float prelu_f(float x, float a) { return x >= 0.f ? x : a * x; }

// 16-lane reduce via DPP row_ror — VALU pipe only; result valid in all 16 lanes.
#define ROR_F(x, n) __int_as_float(__builtin_amdgcn_update_dpp(0, __float_as_int(x), 0x120 + (n), 0xf, 0xf, true))
__device__ __forceinline__ float row_sum16(float x) {
    x += ROR_F(x, 1); x += ROR_F(x, 2); x += ROR_F(x, 4); x += ROR_F(x, 8);
    return x;
}
__device__ __forceinline__ float row_max16(float x) {
    x = fmaxf(x, ROR_F(x, 1)); x = fmaxf(x, ROR_F(x, 2));
    x = fmaxf(x, ROR_F(x, 4)); x = fmaxf(x, ROR_F(x, 8));
    return x;
}

// ---------------- prep: W_k|W_v -> bf16 [256 rows][512B], XOR-swizzled within rows
__global__ void prep_kernel(const float* __restrict__ Wk, const float* __restrict__ Wv,
                            __hip_bfloat16* __restrict__ Wb) {
    int idx = blockIdx.x * 256 + threadIdx.x;   // 256 blocks -> 65536
    int a = idx >> 8, d = idx & 255;
    float v = (a < 128) ? Wk[a * 256 + d] : Wv[(a - 128) * 256 + d];
    int boff = (d * 2) ^ ((a & 7) << 4);
    Wb[a * 256 + (boff >> 1)] = __float2bfloat16(v);
}

// per-thread staging for stream s
#define ISSUE(tt, s)                                                            \
    {                                                                           \
        int r_ = (tt) * 16 + srow; r_ = r_ < SS ? r_ : SS - 1;                  \
        const float* xp_ = Xp##s + (size_t)r_ * DSEQ + chunk * 8;               \
        stlo##s = *reinterpret_cast<const f32x4*>(xp_);                         \
        sthi##s = *reinterpret_cast<const f32x4*>(xp_ + 4);                     \
    }

#define STAGE(buf, s)                                                           \
    {                                                                           \
        bf16x8 v_;                                                              \
        v_[0] = (__bf16)stlo##s[0]; v_[1] = (__bf16)stlo##s[1];                 \
        v_[2] = (__bf16)stlo##s[2]; v_[3] = (__bf16)stlo##s[3];                 \
        v_[4] = (__bf16)sthi##s[0]; v_[5] = (__bf16)sthi##s[1];                 \
        v_[6] = (__bf16)sthi##s[2]; v_[7] = (__bf16)sthi##s[3];                 \
        *reinterpret_cast<bf16x8*>(xb##s + (buf) * 8192 + wr_off) = v_;         \
    }

// deferred online-softmax + V-fold of tile `tp`, stream s
#define SMFOLD(tp, s)                                                           \
    {                                                                           \
        const int q_ = (tp) & 1;                                                \
        const int s0_ = (tp) * 16;                                              \
        f32x4 r0_ = *reinterpret_cast<const f32x4*>(&sp##s[q_][c][0]);          \
        f32x4 r1_ = *reinterpret_cast<const f32x4*>(&sp##s[q_][c][4]);          \
        float sc_ = (r0_[0]+r0_[1]+r0_[2]+r0_[3]+r1_[0]+r1_[1]+r1_[2]+r1_[3]) * inv_scale; \
        sc_ = mask##s[s0_ + c] ? -1e9f : sc_;                                   \
        if (tid < 16) score_buf##s[s0_ + tid] = sc_;                            \
        float tmax_ = row_max16(sc_);                                           \
        float nm_ = fmaxf(m##s, tmax_);                                         \
        float fs_ = __expf(m##s - nm_);                                         \
        float e_  = __expf(sc_ - nm_);                                          \
        float ls_ = row_sum16(e_);                                              \
        l##s = l##s * fs_ + ls_; m##s = nm_;                                    \
        oacc##s *= fs_;                                                         \
        _Pragma("unroll")                                                       \
        for (int i_ = 0; i_ < 4; i_++) {                                        \
            float ew_ = __shfl(e_, (lane & 48) | (rg * 4 + i_), 64);            \
            oacc##s += ew_ * prelu_f(aVp##s[i_], pa);                           \
        }                                                                       \
    }

// ---------------- main: one BLOCK (8 waves) per TWO batch rows (dual stream).
// K weight frags in VGPRs (shared by both streams); V frags streamed from L2
// once per k and fed to both streams' MFMAs.
__global__ __launch_bounds__(512)
void pool_main(
    const float* __restrict__ X,      // [2048,200,256]
    const int*   __restrict__ maskp,  // [2048,200] 1 = pad
    const float* __restrict__ temb,   // [2048,64]
    const float* __restrict__ Wq,     // [128,64]
    const float* __restrict__ Wker,   // [128,128]
    const float* __restrict__ ffnW,   // [256,128]
    const float* __restrict__ ffnb,   // [256]
    const float* __restrict__ prelu_a,
    const __hip_bfloat16* __restrict__ Wb,  // ws: swizzled bf16 weights [256][256]
    float* __restrict__ out)          // [2048*256] ffn, then [2048*200] attn
{
    __shared__ __hip_bfloat16 Xt0[2][16][256];   // 16 KB
    __shared__ __hip_bfloat16 Xt1[2][16][256];   // 16 KB
    __shared__ float sp0[2][16][8], sp1[2][16][8];
    __shared__ float score_buf0[208], score_buf1[208];
    __shared__ float out_vec0[AA], out_vec1[AA];
    __shared__ float tq0[DITEM], tq1[DITEM];
    __shared__ float Qv0[AA], Qv1[AA];
    __shared__ float uv0[AA], uv1[AA];
    __shared__ int   mask0[208], mask1[208];

    const int tid  = threadIdx.x;
    const int w    = tid >> 6;        // wave 0..7
    const int lane = tid & 63;
    const int c    = lane & 15;
    const int rg   = lane >> 4;
    const int b0   = blockIdx.x * 2;
    const int b1   = b0 + 1;
    const float pa = *prelu_a;
    const float inv_scale = 0.08838834764831845f;  // 1/sqrt(128)

    const int srow  = tid >> 5;       // staging row 0..15
    const int chunk = tid & 31;       // 32B chunk in row
    const int wr_off = srow * 512 + ((chunk * 16) ^ ((srow & 7) << 4));
    char* xb0 = (char*)&Xt0[0][0][0];
    char* xb1 = (char*)&Xt1[0][0][0];
    const int rswz = (c & 7) << 4;
    const float* Xp0 = X + (size_t)b0 * SS * DSEQ;
    const float* Xp1 = X + (size_t)b1 * SS * DSEQ;

    // ---- K weight fragments -> VGPRs (shared by both streams); V stays in L2
    bf16x8 wk[8];
    const char* kb = (const char*)Wb + (size_t)(16 * w + c) * 512;
    const char* vb = kb + 65536;
    #pragma unroll
    for (int k = 0; k < 8; k++)
        wk[k] = *reinterpret_cast<const bf16x8*>(kb + ((k * 64 + rg * 16) ^ rswz));

    // ---- small staging (both streams in parallel) + X tile-0 issue
    if (tid < DITEM)                     tq0[tid]       = temb[(size_t)b0 * DITEM + tid];
    else if (tid < 2 * DITEM)            tq1[tid - 64]  = temb[(size_t)b1 * DITEM + tid - 64];
    if (tid < 208)                       mask0[tid]        = (tid < SS) ? maskp[(size_t)b0 * SS + tid] : 1;
    else if (tid >= 256 && tid < 464)    mask1[tid - 256]  = (tid - 256 < SS) ? maskp[(size_t)b1 * SS + tid - 256] : 1;
    f32x4 stlo0, sthi0, stlo1, sthi1;
    ISSUE(0, 0); ISSUE(0, 1);
    __syncthreads();

    // ---- Q for both streams (threads 0..127 -> b0, 128..255 -> b1)
    if (tid < 256) {
        const int o = tid & 127;
        const float* tqp = (tid < 128) ? tq0 : tq1;
        float acc = 0.f;
        #pragma unroll
        for (int d4 = 0; d4 < 16; d4++) {
            f32x4 tv = *reinterpret_cast<const f32x4*>(&tqp[d4 * 4]);
            f32x4 wq4 = *reinterpret_cast<const f32x4*>(Wq + (size_t)o * DITEM + d4 * 4);
            acc += wq4[0]*tv[0] + wq4[1]*tv[1] + wq4[2]*tv[2] + wq4[3]*tv[3];
        }
        if (tid < 128) Qv0[o] = prelu_f(acc, pa); else Qv1[o] = prelu_f(acc, pa);
    }
    __syncthreads();

    // ---- u for both streams
    if (tid < 256) {
        const int o = tid & 127;
        const float* qp = (tid < 128) ? Qv0 : Qv1;
        float acc = 0.f;
        #pragma unroll
        for (int d4 = 0; d4 < 32; d4++) {
            f32x4 qv = *reinterpret_cast<const f32x4*>(&qp[d4 * 4]);
            f32x4 wv4 = *reinterpret_cast<const f32x4*>(Wker + (size_t)o * AA + d4 * 4);
            acc += wv4[0]*qv[0] + wv4[1]*qv[1] + wv4[2]*qv[2] + wv4[3]*qv[3];
        }
        if (tid < 128) uv0[o] = acc; else uv1[o] = acc;
    }
    __syncthreads();
    const float uwK0 = uv0[16 * w + c];
    const float uwK1 = uv1[16 * w + c];

    // tile 0 -> LDS, both streams
    STAGE(0, 0); STAGE(0, 1);
    __syncthreads();

    // ---- main loop: 1 barrier per tile, two interleaved independent streams
    float m0 = -INFINITY, l0 = 0.f, oacc0 = 0.f;
    float m1 = -INFINITY, l1 = 0.f, oacc1 = 0.f;
    f32x4 aVp0 = {0.f,0.f,0.f,0.f}, aVp1 = {0.f,0.f,0.f,0.f};

    for (int t = 0; t < NTIL; t++) {
        if (t + 1 < NTIL) { ISSUE(t + 1, 0); ISSUE(t + 1, 1); }

        const char* rb0 = xb0 + (t & 1) * 8192 + c * 512;
        const char* rb1 = xb1 + (t & 1) * 8192 + c * 512;

        if (t > 0) { SMFOLD(t - 1, 0); SMFOLD(t - 1, 1); }

        // dual-stream MFMA: V-frag loaded from L2 once, feeds both streams
        f32x4 aK0 = {0.f,0.f,0.f,0.f}, aV0 = {0.f,0.f,0.f,0.f};
        f32x4 aK1 = {0.f,0.f,0.f,0.f}, aV1 = {0.f,0.f,0.f,0.f};
        #pragma unroll
        for (int k = 0; k < 8; k++) {
            const int o = (k * 64 + rg * 16) ^ rswz;
            bf16x8 bv  = *reinterpret_cast<const bf16x8*>(vb + o);   // L2 hit, shared
            bf16x8 af0 = *reinterpret_cast<const bf16x8*>(rb0 + o);
            bf16x8 af1 = *reinterpret_cast<const bf16x8*>(rb1 + o);
            aK0 = __builtin_amdgcn_mfma_f32_16x16x32_bf16(af0, wk[k], aK0, 0, 0, 0);
            aK1 = __builtin_amdgcn_mfma_f32_16x16x32_bf16(af1, wk[k], aK1, 0, 0, 0);
            aV0 = __builtin_amdgcn_mfma_f32_16x16x32_bf16(af0, bv,    aV0, 0, 0, 0);
            aV1 = __builtin_amdgcn_mfma_f32_16x16x32_bf16(af1, bv,    aV1, 0, 0, 0);
        }
        float pr0[4], pr1[4];
        #pragma unroll
        for (int i = 0; i < 4; i++) {
            pr0[i] = row_sum16(prelu_f(aK0[i], pa) * uwK0);
            pr1[i] = row_sum16(prelu_f(aK1[i], pa) * uwK1);
        }
        if (c == 0) {
            #pragma unroll
            for (int i = 0; i < 4; i++) {
                sp0[t & 1][rg * 4 + i][w] = pr0[i];
                sp1[t & 1][rg * 4 + i][w] = pr1[i];
            }
        }
        aVp0 = aV0; aVp1 = aV1;

        if (t + 1 < NTIL) { STAGE((t + 1) & 1, 0); STAGE((t + 1) & 1, 1); }
        __syncthreads();
    }

    // ---- epilogue: fold last tile, reduce, outputs (both streams)
    SMFOLD(NTIL - 1, 0); SMFOLD(NTIL - 1, 1);
    oacc0 += __shfl_xor(oacc0, 16, 64); oacc0 += __shfl_xor(oacc0, 32, 64);
    oacc1 += __shfl_xor(oacc1, 16, 64); oacc1 += __shfl_xor(oacc1, 32, 64);
    const float invl0 = 1.0f / l0, invl1 = 1.0f / l1;
    if (lane < 16) {
        out_vec0[16 * w + lane] = oacc0 * invl0;
        out_vec1[16 * w + lane] = oacc1 * invl1;
    }
    __syncthreads();

    // attn outputs
    if (tid < SS)
        out[(size_t)NB * DSEQ + (size_t)b0 * SS + tid] = __expf(score_buf0[tid] - m0) * invl0;
    else if (tid >= 256 && tid < 256 + SS)
        out[(size_t)NB * DSEQ + (size_t)b1 * SS + (tid - 256)] = __expf(score_buf1[tid - 256] - m1) * invl1;

    // FFN: threads 0..255 -> b0, 256..511 -> b1
    {
        const int o = tid & 255;
        const float* ovp = (tid < 256) ? out_vec0 : out_vec1;
        const int bo = (tid < 256) ? b0 : b1;
        float acc = ffnb[o];
        #pragma unroll 8
        for (int a4 = 0; a4 < 32; a4++) {
            f32x4 ov = *reinterpret_cast<const f32x4*>(&ovp[a4 * 4]);
            f32x4 wv4 = *reinterpret_cast<const f32x4*>(ffnW + (size_t)o * AA + a4 * 4);
            acc += wv4[0]*ov[0] + wv4[1]*ov[1] + wv4[2]*ov[2] + wv4[3]*ov[3];
        }
        out[(size_t)bo * DSEQ + o] = prelu_f(acc, pa);
    }
}

extern "C" void kernel_launch(void* const* d_in, const int* in_sizes, int n_in,
                              void* d_out, int out_size, void* d_ws, size_t ws_size,
                              hipStream_t stream) {
    const float* X    = (const float*)d_in[0];
    const int*   mask = (const int*)  d_in[1];
    const float* temb = (const float*)d_in[2];
    const float* Wq   = (const float*)d_in[3];
    const float* Wk   = (const float*)d_in[4];
    const float* Wv   = (const float*)d_in[5];
    const float* Wker = (const float*)d_in[6];
    const float* ffnW = (const float*)d_in[7];
    const float* ffnb = (const float*)d_in[8];
    const float* pa   = (const float*)d_in[9];
    float* out = (float*)d_out;

    __hip_bfloat16* Wb = (__hip_bfloat16*)d_ws;

    prep_kernel<<<256, 256, 0, stream>>>(Wk, Wv, Wb);
    pool_main<<<NB / 2, 512, 0, stream>>>(X, mask, temb, Wq, Wker, ffnW, ffnb, pa, Wb, out);
}